// Round 14
// baseline (154.154 us; speedup 1.0000x reference)
//
#include <hip/hip_runtime.h>
#include <stdint.h>

#define NSTEP 365
#define NGRID 4000
#define CAPMIN 0.00125f
#define SMINV 0.0001f
#define PSTR_DW (NGRID * 88)
#define XSTR_DW (NGRID * 3)

// LDS layout (dwords), total 15360 dw = 61440 B:
//   raw ring:     3 regions x 5 slots x 384                        [0, 5760)
//   derived ring: 2 regions x 5 slots x 896 (7 float2 rows)        [5760, 14720)
//   smq staging:  5 x 64                                           [14720, 15040)
//   sme staging:  5 x 64                                           [15040, 15360)
#define RAW_SLOT 384
#define RAW_REG  1920
#define DER_BASE 5760
#define DER_SLOT 896
#define DER_REG  4480
#define SMQ_BASE 14720
#define SME_BASE 15040

typedef __attribute__((address_space(3))) uint32_t lds_u32_t;
typedef __attribute__((address_space(1))) uint32_t glb_u32_t;

__device__ __forceinline__ void dma4(const float* g, float* l) {
    __builtin_amdgcn_global_load_lds((const glb_u32_t*)(const void*)g,
                                     (lds_u32_t*)(void*)l, 4, 0, 0);
}

__device__ __forceinline__ float frcp(float x) { return __builtin_amdgcn_rcpf(x); }
__device__ __forceinline__ float fexp2(float x) { return __builtin_amdgcn_exp2f(x); }
__device__ __forceinline__ float flog2(float x) { return __builtin_amdgcn_logf(x); }

__device__ __forceinline__ void issue_slot(const float* pp, const float* px,
                                           int t, float* dst) {
    const float* pj = pp + (size_t)t * PSTR_DW;
    dma4(pj,      dst);
    dma4(pj + 8,  dst + 64);
    dma4(pj + 16, dst + 128);
    dma4(pj + 24, dst + 192);
    dma4(pj + 32, dst + 256);
    dma4(px + (size_t)t * XSTR_DW, dst + 320);
}

// ---- state wave: hoisted reads (named registers, static addresses) ----
// DER_SLOT = 896 dw = 448 float2
#define RDS(j)                                                               \
    const float2 qp_##j = dreg[(j) * 448 + lane];           /* qdir, peff */ \
    const float2 ek_##j = dreg[(j) * 448 +  64 + lane];     /* Ep, kuz   */ \
    const float2 iu_##j = dreg[(j) * 448 + 128 + lane];     /* 1/uztwm, 1/uzfwm */\
    const float2 hl_##j = dreg[(j) * 448 + 192 + lane];     /* hmean, lztwm */\
    const float2 ip_##j = dreg[(j) * 448 + 256 + lane];     /* 1/lztwm, pbase */\
    const float2 lz_##j = dreg[(j) * 448 + 320 + lane];     /* lzfwpm, lzfwsm */\
    const float2 pz_##j = dreg[(j) * 448 + 384 + lane];     /* pz, 1/defmax */

#define STEP(j) do {                                                         \
    const float qdir = qp_##j.x, peff = qp_##j.y;                            \
    const float Ep = ek_##j.x, kuz = ek_##j.y;                               \
    const float inv_uztwm = iu_##j.x, inv_uzfwm = iu_##j.y;                  \
    const float hmean = hl_##j.x, lztwm = hl_##j.y;                          \
    const float inv_lztwm = ip_##j.x, pbase = ip_##j.y;                      \
    const float lzfwpm = lz_##j.x, lzfwsm = lz_##j.y;                        \
    const float pz = pz_##j.x, inv_defmax = pz_##j.y;                        \
    const float r1 = S1 * inv_uztwm;                                         \
    const float r2 = S2 * inv_uzfwm;                                         \
    const float euztw = fminf(r1 * Ep, S1);                                  \
    const float twexu = (r1 >= 1.0f) ? peff : 0.0f;                          \
    const float qsur  = (r2 >= 1.0f) ? twexu : 0.0f;                         \
    const float rd = r2 - r1;                                                \
    const float ru = (rd > 0.0f) ? rd * hmean : 0.0f;                        \
    const float qint = kuz * S2;                                             \
    const float euzfw = fminf(fmaxf(0.0f, Ep - euztw), S2);                  \
    const float t3 = lztwm - S3, t4 = lzfwpm - S4, t5 = lzfwsm - S5;         \
    const float deficit = fmaxf(1e-8f, t3) + fmaxf(1e-8f, t4)                \
                        + fmaxf(1e-8f, t5);                                  \
    const float powterm = fexp2(e1 * flog2(deficit * inv_defmax));           \
    const float pc = fminf((pbase + pz * powterm) * r2, S2);                 \
    const float pctw = pfree1m * pc;                                         \
    const float ev3 = fmaxf(0.0f, Ep - euztw - euzfw);                       \
    const float elztw = fminf(S3 * inv_lztwm * ev3, S3);                     \
    const float twexl = (S3 >= lztwm) ? pctw : 0.0f;                         \
    const float aa = fmaxf(0.0f, t4) * lzfwsm;                               \
    const float bb = fmaxf(0.0f, t5) * lzfwpm;                               \
    const float den = aa + bb;                                               \
    const float pm = lzfwpm + lzfwsm;                                        \
    const float fp = ((den > 0.0f) ? aa : lzfwpm)                            \
                   * frcp((den > 0.0f) ? den : pm);                          \
    const float fs = 1.0f - fp;                                              \
    const float pcp = pfree * pc;                                            \
    const float twexlp = fp * twexl, twexls = fs * twexl;                    \
    const float pcfwp = fp * pcp, pcfws = fs * pcp;                          \
    const bool rlm = S3 * pm < (S4 + S5) * lztwm;                            \
    const float rlp = rlm ? (S4 * lztwm - S3 * lzfwpm) * inv_defmax : 0.0f;  \
    const float rls = rlm ? (S5 * lztwm - S3 * lzfwsm) * inv_defmax : 0.0f;  \
    const float qbfp = klzp * S4, qbfs = klzs * S5;                          \
    S1 = fmaxf(S1 + peff + ru - euztw - twexu, SMINV);                       \
    S2 = fmaxf(S2 + twexu - euzfw - qsur - qint - ru - pc, SMINV);           \
    S3 = fmaxf(S3 + pctw + rlp + rls - elztw - twexl, SMINV);                \
    S4 = fmaxf(S4 + twexlp + pcfwp - rlp - qbfp, SMINV);                     \
    S5 = fmaxf(S5 + twexls + pcfws - rls - qbfs, SMINV);                     \
    smq[(j) * 64 + lane] = qdir + qsur + qint + qbfp + qbfs;                 \
    sme[(j) * 64 + lane] = euztw + euzfw + elztw;                            \
} while (0)

__global__ __launch_bounds__(192, 1) void sacsma_kernel(
    const float* __restrict__ x,     // [NSTEP][NGRID][3]
    const float* __restrict__ par,   // [NSTEP][NGRID][11][8]
    float* __restrict__ out)         // [NSTEP][NGRID][2]
{
    __shared__ __align__(16) float lds[15360];   // 61440 B

    const int wave = threadIdx.x >> 6;
    const int lane = threadIdx.x & 63;
    const int g0   = blockIdx.x * 8;
    const int gl   = lane >> 3;
    const int mu   = lane & 7;
    const int g    = g0 + gl;
    const int gl3  = gl * 3;

    if (wave == 0) {
        // ===== DMA producer (r9-verbatim except 3-region ring) =====
        const float* pp = par + (size_t)g * 88 + mu;
        int xl = lane; if (xl >= 24) xl -= 24; if (xl >= 24) xl -= 24;
        const int xq = xl / 3;
        const float* px = x + (g0 + xq) * 3 + (xl - xq * 3);

        #pragma unroll
        for (int j = 0; j < 5; ++j)
            issue_slot(pp, px, j, lds + j * RAW_SLOT);

        for (int i = 0; i < 75; ++i) {
            if (i <= 71) {
                const int b = i + 1;                   // batches 1..72
                float* dst = lds + (b % 3) * RAW_REG;
                const int tb = 5 * b;
                #pragma unroll
                for (int j = 0; j < 5; ++j)
                    issue_slot(pp, px, tb + j, dst + j * RAW_SLOT);
                // batch i (issued one iter ago) retired; 30 newest = batch i+1
                asm volatile("s_waitcnt vmcnt(30)" ::: "memory");
            } else {
                asm volatile("s_waitcnt vmcnt(0)" ::: "memory");
            }
            asm volatile("s_barrier" ::: "memory");
        }
    } else if (wave == 1) {
        // ===== transform wave: raw -> derived (param-only math, off the S-chain) =====
        const float* ps = par + ((size_t)(NSTEP - 1) * NGRID + g) * 88 + mu;
        const float f3   = 0.005f + ps[6 * 8] * 0.99f;
        const float f4   = 0.005f + ps[7 * 8] * 0.99f;
        const float klzp = ps[9 * 8];
        const float klzs = ps[10 * 8];
        const float f4m  = 1.0f - f4;
        const float k1p  = 1.0f - klzp;
        const float k1s  = 1.0f - klzs;

        for (int i = 0; i < 75; ++i) {
            if (i >= 1 && i <= 73) {
                const int b = i - 1;                   // batches 0..72
                const float* rreg = lds + (b % 3) * RAW_REG;
                float* dregf = lds + DER_BASE + (b & 1) * DER_REG;
                #pragma unroll
                for (int j = 0; j < 5; ++j) {
                    const float* rb = rreg + j * RAW_SLOT;
                    float2* db = reinterpret_cast<float2*>(dregf + j * DER_SLOT);

                    const float c0 = rb[lane];
                    const float c1 = rb[64 + lane];
                    const float c2 = rb[128 + lane];
                    const float c3 = rb[192 + lane];
                    const float c4 = rb[256 + lane];
                    const float P  = rb[320 + gl3];
                    const float Ep = rb[322 + gl3];

                    const float smaxv = 1.0f + c1 * 1999.0f;
                    const float f1 = 0.005f + c2 * 0.99f;
                    const float f2 = 0.005f + c3 * 0.99f;
                    const float uztwm = f1 * smaxv;
                    float rem = smaxv - uztwm;
                    const float uzfwm = fmaxf(CAPMIN, f2 * rem);
                    rem -= uzfwm;
                    const float lztwm = fmaxf(CAPMIN, f3 * rem);
                    rem -= lztwm;
                    const float lzfwpm = fmaxf(CAPMIN, f4 * rem);
                    const float lzfwsm = fmaxf(CAPMIN, f4m * rem);
                    const float pbase = lzfwpm * klzp + lzfwsm * klzs;
                    const float pzv = fminf(lztwm + lzfwsm * k1s + lzfwpm * k1p,
                                            100000.0f * pbase);
                    const float inv_uztwm = frcp(uztwm);
                    const float inv_uzfwm = frcp(uzfwm);
                    const float inv_lztwm = frcp(lztwm);
                    const float hmean = uztwm * uzfwm * frcp(uztwm + uzfwm);
                    const float inv_defmax = frcp(lztwm + lzfwpm + lzfwsm);
                    const float qdir = c0 * P;

                    db[0 * 64 + lane] = make_float2(qdir, P - qdir);
                    db[1 * 64 + lane] = make_float2(Ep, c4);
                    db[2 * 64 + lane] = make_float2(inv_uztwm, inv_uzfwm);
                    db[3 * 64 + lane] = make_float2(hmean, lztwm);
                    db[4 * 64 + lane] = make_float2(inv_lztwm, pbase);
                    db[5 * 64 + lane] = make_float2(lzfwpm, lzfwsm);
                    db[6 * 64 + lane] = make_float2(pzv, inv_defmax);
                }
                asm volatile("s_waitcnt lgkmcnt(0)" ::: "memory");
            }
            asm volatile("s_barrier" ::: "memory");
        }
    } else {
        // ===== state wave: slimmed recurrence + reduction (r9 placement), no setprio =====
        const float* ps = par + ((size_t)(NSTEP - 1) * NGRID + g) * 88 + mu;
        const float e1    = 1.0f + ps[5 * 8] * 7.0f;
        const float pfree = ps[8 * 8];
        const float klzp  = ps[9 * 8];
        const float klzs  = ps[10 * 8];
        const float pfree1m = 1.0f - pfree;

        float S1 = 0.001f, S2 = 0.001f, S3 = 0.001f, S4 = 0.001f, S5 = 0.001f;
        float* smq = lds + SMQ_BASE;
        float* sme = lds + SME_BASE;

        for (int i = 0; i < 75; ++i) {
            if (i >= 2) {
                const int b = i - 2;                   // batches 0..72
                const float2* dreg = reinterpret_cast<const float2*>(
                    lds + DER_BASE + (b & 1) * DER_REG);

                RDS(0) RDS(1) RDS(2) RDS(3) RDS(4)
                STEP(0); STEP(1); STEP(2); STEP(3); STEP(4);

                if (lane < 40) {
                    const int s  = lane >> 3;
                    const int gg = lane & 7;
                    const float4* q4 = reinterpret_cast<const float4*>(&smq[s * 64 + gg * 8]);
                    const float4* e4 = reinterpret_cast<const float4*>(&sme[s * 64 + gg * 8]);
                    const float4 qa = q4[0], qb = q4[1];
                    const float4 ea = e4[0], eb = e4[1];
                    const float qsum = ((qa.x + qa.y) + (qa.z + qa.w))
                                     + ((qb.x + qb.y) + (qb.z + qb.w));
                    const float esum = ((ea.x + ea.y) + (ea.z + ea.w))
                                     + ((eb.x + eb.y) + (eb.z + eb.w));
                    float2 o = make_float2(qsum * 0.125f, esum * 0.125f);
                    *reinterpret_cast<float2*>(
                        out + ((size_t)(5 * b + s) * NGRID + g0 + gg) * 2) = o;
                }
            }
            asm volatile("s_barrier" ::: "memory");
        }
    }
}

extern "C" void kernel_launch(void* const* d_in, const int* in_sizes, int n_in,
                              void* d_out, int out_size, void* d_ws, size_t ws_size,
                              hipStream_t stream) {
    const float* x   = (const float*)d_in[0];   // (365, 4000, 3)
    const float* par = (const float*)d_in[1];   // (365, 4000, 11, 8)
    float* out = (float*)d_out;                 // (365, 4000, 2)

    sacsma_kernel<<<NGRID / 8, 192, 0, stream>>>(x, par, out);  // 500 WGs x 3 waves
}